// Round 1
// baseline (248.385 us; speedup 1.0000x reference)
//
#include <hip/hip_runtime.h>
#include <cmath>

// LocalHolder2D: out = w3*log10(maxpool3(x)) + w5*log10(maxpool5(x)) + w7*log10(maxpool7(x))
// x: (8,64,256,256) fp32, strictly positive => -inf padding == 0 padding.
// Separable maxpool: vertical (register rolling window) then horizontal
// (per-lane prefix/suffix maxes + lane+-1 shuffles). One wave = one full
// 256-wide row (64 lanes x float4). No LDS, no __syncthreads.

#define IMG_H 256
#define IMG_W 256
#define RPW   64   // rows per wave; 4 waves/block cover one 256-row image

__device__ __forceinline__ float4 f4max(float4 a, float4 b) {
  return make_float4(fmaxf(a.x, b.x), fmaxf(a.y, b.y),
                     fmaxf(a.z, b.z), fmaxf(a.w, b.w));
}

struct PS { float p1, p2, p3, s1, s2, s3, f; };

__device__ __forceinline__ PS make_ps(float4 a) {
  PS r;
  r.p1 = a.x;
  r.p2 = fmaxf(a.x, a.y);
  r.p3 = fmaxf(r.p2, a.z);
  r.s1 = a.w;
  r.s2 = fmaxf(a.z, a.w);
  r.s3 = fmaxf(a.y, r.s2);
  r.f  = fmaxf(r.p2, r.s2);
  return r;
}

__global__ __launch_bounds__(256, 2) void holder_kernel(
    const float* __restrict__ x, float* __restrict__ out,
    float w3, float w5, float w7)
{
  const int lane = threadIdx.x & 63;
  const int wave = threadIdx.x >> 6;
  const int img  = blockIdx.x;
  const int r0   = wave * RPW;

  const float* px = x   + (size_t)img * (IMG_H * IMG_W) + lane * 4;
  float*       po = out + (size_t)img * (IMG_H * IMG_W) + lane * 4;

  const float4 zero = make_float4(0.f, 0.f, 0.f, 0.f);

  // rolling window: win[i] = row (r-3+i) of this lane's 4 columns
  float4 win[7];
#pragma unroll
  for (int i = 0; i < 7; ++i) {
    int rr = r0 - 3 + i;
    win[i] = (rr >= 0 && rr < IMG_H) ? *(const float4*)(px + rr * IMG_W) : zero;
  }

#pragma unroll 4
  for (int r = r0; r < r0 + RPW; ++r) {
    int rn = r + 4;
    float4 nxt = (rn < IMG_H) ? *(const float4*)(px + rn * IMG_W) : zero;

    // vertical maxes, radius 1/2/3
    float4 v1 = f4max(f4max(win[2], win[3]), win[4]);
    float4 v2 = f4max(v1, f4max(win[1], win[5]));
    float4 v3 = f4max(v2, f4max(win[0], win[6]));

    PS a1 = make_ps(v1), a2 = make_ps(v2), a3 = make_ps(v3);

    // left-neighbor suffix maxes (lane-1); zero-pad at lane 0
    float L1s1 = __shfl_up(a1.s1, 1);
    float L2s1 = __shfl_up(a2.s1, 1);
    float L2s2 = __shfl_up(a2.s2, 1);
    float L3s1 = __shfl_up(a3.s1, 1);
    float L3s2 = __shfl_up(a3.s2, 1);
    float L3s3 = __shfl_up(a3.s3, 1);
    if (lane == 0) { L1s1 = 0.f; L2s1 = 0.f; L2s2 = 0.f;
                     L3s1 = 0.f; L3s2 = 0.f; L3s3 = 0.f; }

    // right-neighbor prefix maxes (lane+1); zero-pad at lane 63
    float R1p1 = __shfl_down(a1.p1, 1);
    float R2p1 = __shfl_down(a2.p1, 1);
    float R2p2 = __shfl_down(a2.p2, 1);
    float R3p1 = __shfl_down(a3.p1, 1);
    float R3p2 = __shfl_down(a3.p2, 1);
    float R3p3 = __shfl_down(a3.p3, 1);
    if (lane == 63) { R1p1 = 0.f; R2p1 = 0.f; R2p2 = 0.f;
                      R3p1 = 0.f; R3p2 = 0.f; R3p3 = 0.f; }

    // horizontal maxes per column j=0..3 (thread columns 4*lane + j)
    float m3_0 = fmaxf(L1s1, a1.p2);
    float m3_1 = a1.p3;
    float m3_2 = a1.s3;
    float m3_3 = fmaxf(a1.s2, R1p1);

    float m5_0 = fmaxf(L2s2, a2.p3);
    float m5_1 = fmaxf(L2s1, a2.f);
    float m5_2 = fmaxf(a2.f, R2p1);
    float m5_3 = fmaxf(a2.s3, R2p2);

    float m7_0 = fmaxf(L3s3, a3.f);
    float m7_1 = fmaxf(fmaxf(L3s2, a3.f), R3p1);
    float m7_2 = fmaxf(fmaxf(L3s1, a3.f), R3p2);
    float m7_3 = fmaxf(a3.f, R3p3);

    // weights already include log10(2): out = sum w_i * log2(m_i)
    float4 o;
    o.x = fmaf(w7, __log2f(m7_0), fmaf(w5, __log2f(m5_0), w3 * __log2f(m3_0)));
    o.y = fmaf(w7, __log2f(m7_1), fmaf(w5, __log2f(m5_1), w3 * __log2f(m3_1)));
    o.z = fmaf(w7, __log2f(m7_2), fmaf(w5, __log2f(m5_2), w3 * __log2f(m3_2)));
    o.w = fmaf(w7, __log2f(m7_3), fmaf(w5, __log2f(m5_3), w3 * __log2f(m3_3)));
    *(float4*)(po + r * IMG_W) = o;

    // slide window down one row
    win[0] = win[1]; win[1] = win[2]; win[2] = win[3];
    win[3] = win[4]; win[4] = win[5]; win[5] = win[6];
    win[6] = nxt;
  }
}

extern "C" void kernel_launch(void* const* d_in, const int* in_sizes, int n_in,
                              void* d_out, int out_size, void* d_ws, size_t ws_size,
                              hipStream_t stream) {
  const float* x = (const float*)d_in[0];
  float* out = (float*)d_out;

  const int n_img = in_sizes[0] / (IMG_H * IMG_W);  // B*C = 512

  // closed-form OLS slope weights (H*W cancels in centering), log10(2) folded in
  const double l0 = log10(3.0), l1 = log10(5.0), l2 = log10(7.0);
  const double m  = (l0 + l1 + l2) / 3.0;
  const double c0 = l0 - m, c1 = l1 - m, c2 = l2 - m;
  const double s  = c0 * c0 + c1 * c1 + c2 * c2;
  const double LG2 = 0.30102999566398119521;  // log10(2)
  const float w3 = (float)(c0 / s * LG2);
  const float w5 = (float)(c1 / s * LG2);
  const float w7 = (float)(c2 / s * LG2);

  hipLaunchKernelGGL(holder_kernel, dim3(n_img), dim3(256), 0, stream,
                     x, out, w3, w5, w7);
}

// Round 2
// 242.756 us; speedup vs baseline: 1.0232x; 1.0232x over previous
//
#include <hip/hip_runtime.h>
#include <cmath>

// LocalHolder2D: out = w3*log10(maxpool3(x)) + w5*log10(maxpool5(x)) + w7*log10(maxpool7(x))
// x: (8,64,256,256) fp32, strictly positive => -inf padding == 0 padding.
// Separable maxpool: vertical (register rolling window) then horizontal
// (per-lane prefix/suffix maxes + lane+-1 shuffles). One wave = one full
// 256-wide row (64 lanes x float4). No LDS, no __syncthreads.
//
// R1: grid 512 -> 2048 blocks (4 row-bands/image, 16 rows/wave) to lift
// occupancy from 2 blocks/CU (20%) toward 8 blocks/CU; kernel was
// latency-bound at 2.1 TB/s with VALUBusy 22%.

#define IMG_H 256
#define IMG_W 256
#define RPW   16   // rows per wave; 4 waves/block -> 64-row band per block

__device__ __forceinline__ float4 f4max(float4 a, float4 b) {
  return make_float4(fmaxf(a.x, b.x), fmaxf(a.y, b.y),
                     fmaxf(a.z, b.z), fmaxf(a.w, b.w));
}

struct PS { float p1, p2, p3, s1, s2, s3, f; };

__device__ __forceinline__ PS make_ps(float4 a) {
  PS r;
  r.p1 = a.x;
  r.p2 = fmaxf(a.x, a.y);
  r.p3 = fmaxf(r.p2, a.z);
  r.s1 = a.w;
  r.s2 = fmaxf(a.z, a.w);
  r.s3 = fmaxf(a.y, r.s2);
  r.f  = fmaxf(r.p2, r.s2);
  return r;
}

__global__ __launch_bounds__(256, 8) void holder_kernel(
    const float* __restrict__ x, float* __restrict__ out,
    float w3, float w5, float w7)
{
  const int lane = threadIdx.x & 63;
  const int wave = threadIdx.x >> 6;
  const int img  = blockIdx.x;
  const int band = blockIdx.y;
  const int r0   = band * (4 * RPW) + wave * RPW;

  const float* px = x   + (size_t)img * (IMG_H * IMG_W) + lane * 4;
  float*       po = out + (size_t)img * (IMG_H * IMG_W) + lane * 4;

  const float4 zero = make_float4(0.f, 0.f, 0.f, 0.f);

  // rolling window: win[i] = row (r-3+i) of this lane's 4 columns
  float4 win[7];
#pragma unroll
  for (int i = 0; i < 7; ++i) {
    int rr = r0 - 3 + i;
    win[i] = (rr >= 0 && rr < IMG_H) ? *(const float4*)(px + rr * IMG_W) : zero;
  }

#pragma unroll 4
  for (int r = r0; r < r0 + RPW; ++r) {
    int rn = r + 4;
    float4 nxt = (rn < IMG_H) ? *(const float4*)(px + rn * IMG_W) : zero;

    // vertical maxes, radius 1/2/3
    float4 v1 = f4max(f4max(win[2], win[3]), win[4]);
    float4 v2 = f4max(v1, f4max(win[1], win[5]));
    float4 v3 = f4max(v2, f4max(win[0], win[6]));

    PS a1 = make_ps(v1), a2 = make_ps(v2), a3 = make_ps(v3);

    // left-neighbor suffix maxes (lane-1); zero-pad at lane 0
    float L1s1 = __shfl_up(a1.s1, 1);
    float L2s1 = __shfl_up(a2.s1, 1);
    float L2s2 = __shfl_up(a2.s2, 1);
    float L3s1 = __shfl_up(a3.s1, 1);
    float L3s2 = __shfl_up(a3.s2, 1);
    float L3s3 = __shfl_up(a3.s3, 1);
    if (lane == 0) { L1s1 = 0.f; L2s1 = 0.f; L2s2 = 0.f;
                     L3s1 = 0.f; L3s2 = 0.f; L3s3 = 0.f; }

    // right-neighbor prefix maxes (lane+1); zero-pad at lane 63
    float R1p1 = __shfl_down(a1.p1, 1);
    float R2p1 = __shfl_down(a2.p1, 1);
    float R2p2 = __shfl_down(a2.p2, 1);
    float R3p1 = __shfl_down(a3.p1, 1);
    float R3p2 = __shfl_down(a3.p2, 1);
    float R3p3 = __shfl_down(a3.p3, 1);
    if (lane == 63) { R1p1 = 0.f; R2p1 = 0.f; R2p2 = 0.f;
                      R3p1 = 0.f; R3p2 = 0.f; R3p3 = 0.f; }

    // horizontal maxes per column j=0..3 (thread columns 4*lane + j)
    float m3_0 = fmaxf(L1s1, a1.p2);
    float m3_1 = a1.p3;
    float m3_2 = a1.s3;
    float m3_3 = fmaxf(a1.s2, R1p1);

    float m5_0 = fmaxf(L2s2, a2.p3);
    float m5_1 = fmaxf(L2s1, a2.f);
    float m5_2 = fmaxf(a2.f, R2p1);
    float m5_3 = fmaxf(a2.s3, R2p2);

    float m7_0 = fmaxf(L3s3, a3.f);
    float m7_1 = fmaxf(fmaxf(L3s2, a3.f), R3p1);
    float m7_2 = fmaxf(fmaxf(L3s1, a3.f), R3p2);
    float m7_3 = fmaxf(a3.f, R3p3);

    // weights already include log10(2): out = sum w_i * log2(m_i)
    float4 o;
    o.x = fmaf(w7, __log2f(m7_0), fmaf(w5, __log2f(m5_0), w3 * __log2f(m3_0)));
    o.y = fmaf(w7, __log2f(m7_1), fmaf(w5, __log2f(m5_1), w3 * __log2f(m3_1)));
    o.z = fmaf(w7, __log2f(m7_2), fmaf(w5, __log2f(m5_2), w3 * __log2f(m3_2)));
    o.w = fmaf(w7, __log2f(m7_3), fmaf(w5, __log2f(m5_3), w3 * __log2f(m3_3)));
    *(float4*)(po + r * IMG_W) = o;

    // slide window down one row
    win[0] = win[1]; win[1] = win[2]; win[2] = win[3];
    win[3] = win[4]; win[4] = win[5]; win[5] = win[6];
    win[6] = nxt;
  }
}

extern "C" void kernel_launch(void* const* d_in, const int* in_sizes, int n_in,
                              void* d_out, int out_size, void* d_ws, size_t ws_size,
                              hipStream_t stream) {
  const float* x = (const float*)d_in[0];
  float* out = (float*)d_out;

  const int n_img = in_sizes[0] / (IMG_H * IMG_W);  // B*C = 512

  // closed-form OLS slope weights (H*W cancels in centering), log10(2) folded in
  const double l0 = log10(3.0), l1 = log10(5.0), l2 = log10(7.0);
  const double m  = (l0 + l1 + l2) / 3.0;
  const double c0 = l0 - m, c1 = l1 - m, c2 = l2 - m;
  const double s  = c0 * c0 + c1 * c1 + c2 * c2;
  const double LG2 = 0.30102999566398119521;  // log10(2)
  const float w3 = (float)(c0 / s * LG2);
  const float w5 = (float)(c1 / s * LG2);
  const float w7 = (float)(c2 / s * LG2);

  hipLaunchKernelGGL(holder_kernel, dim3(n_img, 4), dim3(256), 0, stream,
                     x, out, w3, w5, w7);
}

// Round 4
// 241.615 us; speedup vs baseline: 1.0280x; 1.0047x over previous
//
#include <hip/hip_runtime.h>
#include <cmath>

// LocalHolder2D: out = w3*log10(maxpool3(x)) + w5*log10(maxpool5(x)) + w7*log10(maxpool7(x))
// x: (8,64,256,256) fp32, strictly positive => -inf padding == 0 padding.
// Separable maxpool: vertical (register rolling window) then horizontal
// (per-lane prefix/suffix maxes + lane+-1 exchange). One wave = one full
// 256-wide row (64 lanes x float4). No LDS, no __syncthreads.
//
// R1: grid 512 -> 2048 blocks (4 bands/image), occupancy 20% -> 68%.
// R2: lane+-1 exchange via DPP wavefront shifts (bound_ctrl zero-fill)
//     instead of ds_bpermute shuffles + cndmask fixups.
// R3: FIX DPP direction swap: wf_shr1 (0x138) moves data to HIGHER lanes
//     (lane i reads lane i-1); wf_shl1 (0x130) moves data to LOWER lanes
//     (lane i reads lane i+1). R2 had them backwards -> absmax 2.86.

#define IMG_H 256
#define IMG_W 256
#define RPW   16   // rows per wave; 4 waves/block -> 64-row band per block

// lane i <- lane i-1, zero at lane 0  (DPP wf_shr1; invalid lane -> old=0)
__device__ __forceinline__ float dpp_left(float v) {
  return __int_as_float(
      __builtin_amdgcn_update_dpp(0, __float_as_int(v), 0x138, 0xF, 0xF, true));
}
// lane i <- lane i+1, zero at lane 63 (DPP wf_shl1)
__device__ __forceinline__ float dpp_right(float v) {
  return __int_as_float(
      __builtin_amdgcn_update_dpp(0, __float_as_int(v), 0x130, 0xF, 0xF, true));
}

__device__ __forceinline__ float4 f4max(float4 a, float4 b) {
  return make_float4(fmaxf(a.x, b.x), fmaxf(a.y, b.y),
                     fmaxf(a.z, b.z), fmaxf(a.w, b.w));
}

struct PS { float p1, p2, p3, s1, s2, s3, f; };

__device__ __forceinline__ PS make_ps(float4 a) {
  PS r;
  r.p1 = a.x;
  r.p2 = fmaxf(a.x, a.y);
  r.p3 = fmaxf(r.p2, a.z);
  r.s1 = a.w;
  r.s2 = fmaxf(a.z, a.w);
  r.s3 = fmaxf(a.y, r.s2);
  r.f  = fmaxf(r.p2, r.s2);
  return r;
}

__global__ __launch_bounds__(256, 8) void holder_kernel(
    const float* __restrict__ x, float* __restrict__ out,
    float w3, float w5, float w7)
{
  const int lane = threadIdx.x & 63;
  const int wave = threadIdx.x >> 6;
  const int img  = blockIdx.x;
  const int band = blockIdx.y;
  const int r0   = band * (4 * RPW) + wave * RPW;

  const float* px = x   + (size_t)img * (IMG_H * IMG_W) + lane * 4;
  float*       po = out + (size_t)img * (IMG_H * IMG_W) + lane * 4;

  const float4 zero = make_float4(0.f, 0.f, 0.f, 0.f);

  // rolling window: win[i] = row (r-3+i) of this lane's 4 columns
  float4 win[7];
#pragma unroll
  for (int i = 0; i < 7; ++i) {
    int rr = r0 - 3 + i;
    win[i] = (rr >= 0 && rr < IMG_H) ? *(const float4*)(px + rr * IMG_W) : zero;
  }

#pragma unroll 8
  for (int r = r0; r < r0 + RPW; ++r) {
    int rn = r + 4;
    float4 nxt = (rn < IMG_H) ? *(const float4*)(px + rn * IMG_W) : zero;

    // vertical maxes, radius 1/2/3
    float4 v1 = f4max(f4max(win[2], win[3]), win[4]);
    float4 v2 = f4max(v1, f4max(win[1], win[5]));
    float4 v3 = f4max(v2, f4max(win[0], win[6]));

    PS a1 = make_ps(v1), a2 = make_ps(v2), a3 = make_ps(v3);

    // left-neighbor suffix maxes (lane-1); DPP zero-fills lane 0
    float L1s1 = dpp_left(a1.s1);
    float L2s1 = dpp_left(a2.s1);
    float L2s2 = dpp_left(a2.s2);
    float L3s1 = dpp_left(a3.s1);
    float L3s2 = dpp_left(a3.s2);
    float L3s3 = dpp_left(a3.s3);

    // right-neighbor prefix maxes (lane+1); DPP zero-fills lane 63
    float R1p1 = dpp_right(a1.p1);
    float R2p1 = dpp_right(a2.p1);
    float R2p2 = dpp_right(a2.p2);
    float R3p1 = dpp_right(a3.p1);
    float R3p2 = dpp_right(a3.p2);
    float R3p3 = dpp_right(a3.p3);

    // horizontal maxes per column j=0..3 (thread columns 4*lane + j)
    float m3_0 = fmaxf(L1s1, a1.p2);
    float m3_1 = a1.p3;
    float m3_2 = a1.s3;
    float m3_3 = fmaxf(a1.s2, R1p1);

    float m5_0 = fmaxf(L2s2, a2.p3);
    float m5_1 = fmaxf(L2s1, a2.f);
    float m5_2 = fmaxf(a2.f, R2p1);
    float m5_3 = fmaxf(a2.s3, R2p2);

    float m7_0 = fmaxf(L3s3, a3.f);
    float m7_1 = fmaxf(fmaxf(L3s2, a3.f), R3p1);
    float m7_2 = fmaxf(fmaxf(L3s1, a3.f), R3p2);
    float m7_3 = fmaxf(a3.f, R3p3);

    // weights already include log10(2): out = sum w_i * log2(m_i)
    float4 o;
    o.x = fmaf(w7, __log2f(m7_0), fmaf(w5, __log2f(m5_0), w3 * __log2f(m3_0)));
    o.y = fmaf(w7, __log2f(m7_1), fmaf(w5, __log2f(m5_1), w3 * __log2f(m3_1)));
    o.z = fmaf(w7, __log2f(m7_2), fmaf(w5, __log2f(m5_2), w3 * __log2f(m3_2)));
    o.w = fmaf(w7, __log2f(m7_3), fmaf(w5, __log2f(m5_3), w3 * __log2f(m3_3)));
    *(float4*)(po + r * IMG_W) = o;

    // slide window down one row
    win[0] = win[1]; win[1] = win[2]; win[2] = win[3];
    win[3] = win[4]; win[4] = win[5]; win[5] = win[6];
    win[6] = nxt;
  }
}

extern "C" void kernel_launch(void* const* d_in, const int* in_sizes, int n_in,
                              void* d_out, int out_size, void* d_ws, size_t ws_size,
                              hipStream_t stream) {
  const float* x = (const float*)d_in[0];
  float* out = (float*)d_out;

  const int n_img = in_sizes[0] / (IMG_H * IMG_W);  // B*C = 512

  // closed-form OLS slope weights (H*W cancels in centering), log10(2) folded in
  const double l0 = log10(3.0), l1 = log10(5.0), l2 = log10(7.0);
  const double m  = (l0 + l1 + l2) / 3.0;
  const double c0 = l0 - m, c1 = l1 - m, c2 = l2 - m;
  const double s  = c0 * c0 + c1 * c1 + c2 * c2;
  const double LG2 = 0.30102999566398119521;  // log10(2)
  const float w3 = (float)(c0 / s * LG2);
  const float w5 = (float)(c1 / s * LG2);
  const float w7 = (float)(c2 / s * LG2);

  hipLaunchKernelGGL(holder_kernel, dim3(n_img, 4), dim3(256), 0, stream,
                     x, out, w3, w5, w7);
}